// Round 10
// baseline (59.186 us; speedup 1.0000x reference)
//
#include <hip/hip_runtime.h>
#include <math.h>

// Wong-Wang multi-class decision, forward only — FLOAT64 dynamics (r4-r6,r8,r9 passed).
// r10: spine-depth cuts, 19 -> 16 dependent levels (chain-latency bound at 1 wave/SIMD):
//  * butterfly -> 3 PARALLEL xor-broadcasts (0xB1/0x4E/0x1B) at L1; J-combination
//    folded into z's fma tree: z = fma(ZJo, b1+b2, fma(ZJo, b3, w2)),
//    w2 = fma(ZC*Jd, s, tz), tz = fma(ZC, t1, ZK) computed on the PREVIOUS step's
//    noise chain (off-spine). z at L3 (was L6). ZC=-0.154*270, ZK=0.154*108.
//  * tmag = fma(L2E, z, MAGIC) (r6-validated form), nd = tmag-MAGIC.
//  * NR+update fold: corr = fma(-den,y0,2.0) || my0 = m*y0; cand = fma(my0,corr,s9)
//    == m*y0*(2-den*y0) + s9 (1 ulp from 2-fma NR; -1 level).
// All reassociations are 1-ulp-class — the exact change family shown bit-stable
// (absmax 0.078125) across r5->r6->r8->r9.

#define T_STEPS 500
#define BATCH   16384
#define STRIDE  (BATCH * 4)

template <int CTRL>
__device__ __forceinline__ double qperm_d(double v) {
    long long l = __double_as_longlong(v);
    int lo = (int)(l & 0xFFFFFFFFLL);
    int hi = (int)(l >> 32);
    lo = __builtin_amdgcn_mov_dpp(lo, CTRL, 0xF, 0xF, true);
    hi = __builtin_amdgcn_mov_dpp(hi, CTRL, 0xF, 0xF, true);
    return __longlong_as_double(((long long)hi << 32) | (unsigned int)lo);
}

struct WWConst {
    double ZCJd, ZJo;        // ZC*Jd, ZC*Jo
    double base2;            // base*(1-decay), for the t1 recursion
    double decay, sigma, thr;
};

__device__ __forceinline__ void ww_step(
    double& s, double& t1, double& tz, int& dec, int t, float e, const WWConst& C)
{
    const double MAGIC   = 6755399441055744.0;               // 1.5 * 2^52
    const double L2E     = 1.4426950408889634074;
    const double LN2_HI  = 6.93147180369123816490e-01;
    const double LN2_LO  = 1.90821492927058770002e-10;
    const double DEN1    = 1.0 + 1e-6;
    const double G       = -(0.00641 / 0.154);   // up2 = G*(1-s)

    // L1: 3 parallel xor-broadcasts of the quad's other classes + early products
    double b1 = qperm_d<0xB1>(s);                  // xor1 partner
    double b2 = qperm_d<0x4E>(s);                  // xor2 partner
    double b3 = qperm_d<0x1B>(s);                  // xor3 partner
    double w2  = __builtin_fma(C.ZCJd, s, tz);     // ZC*Jd*s + (ZC*t1 + ZK)
    double up2 = __builtin_fma(-G, s, G);          // G*(1-s)
    double s9  = 0.9 * s;
    // L2
    double o1 = b1 + b2;
    double g3 = __builtin_fma(C.ZJo, b3, w2);
    // L3: z = ZC*x + ZK = -0.154*(270x - 108)
    double z  = __builtin_fma(C.ZJo, o1, g3);
    // L4
    double tmag = __builtin_fma(L2E, z, MAGIC);
    double m    = up2 * z;
    // L5
    int    n  = __double2loint(tmag);              // rint(z*log2e)
    double nd = tmag - MAGIC;
    // L6,L7: reduced argument
    double r  = __builtin_fma(-nd, LN2_HI, z);
    r = __builtin_fma(-nd, LN2_LO, r);
    // L8..L11: deg-10 Estrin Taylor for 2^r-ish (exp(r))
    double r2 = r * r;
    double P0 = 1.0 + r;
    double P1 = __builtin_fma(r, 1.0 / 6.0,      0.5);
    double P2 = __builtin_fma(r, 1.0 / 120.0,    1.0 / 24.0);
    double P3 = __builtin_fma(r, 1.0 / 5040.0,   1.0 / 720.0);
    double P4 = __builtin_fma(r, 1.0 / 362880.0, 1.0 / 40320.0);
    double r4 = r2 * r2;
    double Q0 = __builtin_fma(r2, P1, P0);
    double Q1 = __builtin_fma(r2, P3, P2);
    double Q2 = __builtin_fma(r2, 1.0 / 3628800.0, P4);
    double r8 = r4 * r4;
    double p  = __builtin_fma(r8, Q2, __builtin_fma(r4, Q1, Q0));
    double sc = __hiloint2double((1023 + n) << 20, 0);   // 2^n (off spine)
    // L12: den = 1.000001 - p*2^n
    double den = __builtin_fma(-p, sc, DEN1);
    // L13: hardware reciprocal seed
    double y0 = __builtin_amdgcn_rcp(den);
    // L14 (parallel pair)
    double corr = __builtin_fma(-den, y0, 2.0);    // Newton correction factor
    double my0  = m * y0;
    // L15: cand = m*y0*(2-den*y0) + s9  (== s9 + G*(1-s)*z/den, faithful)
    double cand = __builtin_fma(my0, corr, s9);
    // L16: relu folded into max
    s = fmax(cand, s9);

    // noise chain (off-spine): t1 = base + inoise_{t+1}; tz for next step's w2
    t1 = __builtin_fma(t1, C.decay,
                       __builtin_fma(C.sigma, (double)e, C.base2));
    tz = __builtin_fma(-0.154 * 270.0, t1, 0.154 * 108.0);  // ZC*t1 + ZK

    dec = min(dec, (s > C.thr) ? t : 0x3FFFFFFF);  // first crossing
}

__global__ __launch_bounds__(256)
void ww_kernel(const float* __restrict__ in_sig,
               const float* __restrict__ eps0,
               const float* __restrict__ eps,
               const float* __restrict__ Jm,
               const float* __restrict__ pJext,
               const float* __restrict__ pI0,
               const float* __restrict__ pNa,
               const float* __restrict__ pThr,
               float* __restrict__ out)
{
    const int gid = blockIdx.x * blockDim.x + threadIdx.x; // 0..65535

    const double Jext = (double)pJext[0];
    const double I0   = (double)pI0[0];
    const double na   = (double)pNa[0];
    const double ZC   = -0.154 * 270.0;

    WWConst C;
    const double Jd = (double)Jm[0];   // diagonal
    const double Jo = (double)Jm[1];   // off-diagonal
    C.ZCJd  = ZC * Jd;
    C.ZJo   = ZC * Jo;
    C.decay = exp(-5.0);               // exp(-DT/TAU_AMPA)
    C.sigma = na * sqrt((1.0 - exp(-10.0)) / 2.0);
    C.thr   = (double)pThr[0];

    const double base = I0 + Jext * (double)in_sig[gid];
    C.base2 = base * (1.0 - C.decay);

    double s   = 0.1;
    double t1  = base + (double)eps0[gid] * na;    // base + inoise_0
    double tz  = __builtin_fma(ZC, t1, 0.154 * 108.0);
    int    dec = 0x3FFFFFFF;

    // 10-step double-buffered register prefetch; 500 = 25 blocks * 20 steps.
    const float* pu = eps;
    float eA[10], eB[10];
#pragma unroll
    for (int i = 0; i < 10; ++i) eA[i] = pu[(size_t)i * STRIDE + gid];
    pu += (size_t)10 * STRIDE;

    for (int blk = 0; blk < 25; ++blk) {
        const int t0 = blk * 20;
#pragma unroll
        for (int i = 0; i < 10; ++i)
            eB[i] = pu[(size_t)i * STRIDE + gid];
        pu += (size_t)10 * STRIDE;
#pragma unroll
        for (int i = 0; i < 10; ++i)
            ww_step(s, t1, tz, dec, t0 + i, eA[i], C);
        if (blk < 24) {
#pragma unroll
            for (int i = 0; i < 10; ++i)
                eA[i] = pu[(size_t)i * STRIDE + gid];
            pu += (size_t)10 * STRIDE;
        }
#pragma unroll
        for (int i = 0; i < 10; ++i)
            ww_step(s, t1, tz, dec, t0 + 10 + i, eB[i], C);
    }

    const int d = min(dec, T_STEPS - 1);   // never-crossed -> T-1
    out[gid] = ((float)d * 10.0f) / 1000.0f;
}

extern "C" void kernel_launch(void* const* d_in, const int* in_sizes, int n_in,
                              void* d_out, int out_size, void* d_ws, size_t ws_size,
                              hipStream_t stream) {
    const float* in_sig = (const float*)d_in[0];
    const float* eps0   = (const float*)d_in[1];
    const float* eps    = (const float*)d_in[2];
    const float* Jm     = (const float*)d_in[3];
    const float* pJext  = (const float*)d_in[4];
    const float* pI0    = (const float*)d_in[5];
    const float* pNa    = (const float*)d_in[6];
    const float* pThr   = (const float*)d_in[7];
    float* out = (float*)d_out;

    ww_kernel<<<(BATCH * 4) / 256, 256, 0, stream>>>(
        in_sig, eps0, eps, Jm, pJext, pI0, pNa, pThr, out);
}

// Round 11
// 57.005 us; speedup vs baseline: 1.0383x; 1.0383x over previous
//
#include <hip/hip_runtime.h>
#include <math.h>

// Wong-Wang multi-class decision, forward only — FLOAT64 dynamics (r4-r6,r8-r10 passed).
// r11: issue-count consolidation (r10 post-mortem: depth cuts alone are a wash;
// regime is balanced issue+latency — cut INSTRUCTIONS, hold depth):
//  * butterfly quad-sum restored (r9 form: 4 DPP movs + 2 adds; r10's 3-broadcast
//    cost 2 extra movs + 1 fma for no measured gain)
//  * z = fma(ZJo, sum4, w2), w2 = fma(ZC*(Jd-Jo), s, tz) — tz carried off-spine
//    (r10's trick, kept), sum4 includes s so the self-term uses (Jd-Jo)
//  * SINGLE-LN2 reduction: r = fma(-nd, LN2, z) — err <= |nd|*2^-54 ~ 2e-15,
//    and EXACTLY 0 at the den~0 pole (pole <=> z~0 <=> nd=0). -1 op, -1 level.
//  * corr-fold NR kept: corr = fma(-den,y0,2) || my0 = m*y0; cand = fma(my0,corr,s9)
//  * deg-10 Estrin, DEN1 fold, relu-as-max, t1 recursion, SALU-uniform loads kept.

#define T_STEPS 500
#define BATCH   16384
#define STRIDE  (BATCH * 4)

template <int CTRL>
__device__ __forceinline__ double qperm_d(double v) {
    long long l = __double_as_longlong(v);
    int lo = (int)(l & 0xFFFFFFFFLL);
    int hi = (int)(l >> 32);
    lo = __builtin_amdgcn_mov_dpp(lo, CTRL, 0xF, 0xF, true);
    hi = __builtin_amdgcn_mov_dpp(hi, CTRL, 0xF, 0xF, true);
    return __longlong_as_double(((long long)hi << 32) | (unsigned int)lo);
}

struct WWConst {
    double ZJo, ZCJdmJo;     // ZC*Jo, ZC*(Jd-Jo)
    double base2;            // base*(1-decay), for the t1 recursion
    double decay, sigma, thr;
};

__device__ __forceinline__ void ww_step(
    double& s, double& t1, double& tz, int& dec, int t, float e, const WWConst& C)
{
    const double MAGIC = 6755399441055744.0;               // 1.5 * 2^52
    const double L2E   = 1.4426950408889634074;
    const double LN2   = 6.93147180559945286227e-01;       // correctly-rounded ln2
    const double DEN1  = 1.0 + 1e-6;
    const double G     = -(0.00641 / 0.154);               // up2 = G*(1-s)

    // butterfly quad sum (includes own s): sum4 = s0+s1+s2+s3
    double v1   = s + qperm_d<0xB1>(s);
    double sum4 = v1 + qperm_d<0x4E>(v1);
    double w2   = __builtin_fma(C.ZCJdmJo, s, tz);   // ZC*(Jd-Jo)*s + (ZC*t1 + ZK)
    double up2  = __builtin_fma(-G, s, G);           // G*(1-s), early
    double s9   = 0.9 * s;                           // early
    // z = ZC*x + ZK = -0.154*(270x - 108),  x = Jo*sum4 + (Jd-Jo)*s + t1
    double z = __builtin_fma(C.ZJo, sum4, w2);

    double tmag = __builtin_fma(L2E, z, MAGIC);
    double m    = up2 * z;                           // parallel with exp chain
    int    n    = __double2loint(tmag);              // rint(z*log2e)
    double nd   = tmag - MAGIC;
    double r    = __builtin_fma(-nd, LN2, z);        // single-constant reduction

    // deg-10 Estrin Taylor for exp(r)
    double r2 = r * r;
    double P0 = 1.0 + r;
    double P1 = __builtin_fma(r, 1.0 / 6.0,      0.5);
    double P2 = __builtin_fma(r, 1.0 / 120.0,    1.0 / 24.0);
    double P3 = __builtin_fma(r, 1.0 / 5040.0,   1.0 / 720.0);
    double P4 = __builtin_fma(r, 1.0 / 362880.0, 1.0 / 40320.0);
    double r4 = r2 * r2;
    double Q0 = __builtin_fma(r2, P1, P0);
    double Q1 = __builtin_fma(r2, P3, P2);
    double Q2 = __builtin_fma(r2, 1.0 / 3628800.0, P4);
    double r8 = r4 * r4;
    double p  = __builtin_fma(r8, Q2, __builtin_fma(r4, Q1, Q0));
    double sc = __hiloint2double((1023 + n) << 20, 0);   // 2^n (off spine)

    // den = 1.000001 - p*2^n
    double den = __builtin_fma(-p, sc, DEN1);

    // y ~ 1/den via rcp + folded Newton; cand = m*y0*(2-den*y0) + s9
    double y0   = __builtin_amdgcn_rcp(den);
    double corr = __builtin_fma(-den, y0, 2.0);
    double my0  = m * y0;
    double cand = __builtin_fma(my0, corr, s9);
    s = fmax(cand, s9);                              // relu folded into max

    // noise chain (off-spine): t1 = base + inoise_{t+1}; tz for next step's w2
    t1 = __builtin_fma(t1, C.decay,
                       __builtin_fma(C.sigma, (double)e, C.base2));
    tz = __builtin_fma(-0.154 * 270.0, t1, 0.154 * 108.0);  // ZC*t1 + ZK

    dec = min(dec, (s > C.thr) ? t : 0x3FFFFFFF);    // first crossing
}

__global__ __launch_bounds__(256)
void ww_kernel(const float* __restrict__ in_sig,
               const float* __restrict__ eps0,
               const float* __restrict__ eps,
               const float* __restrict__ Jm,
               const float* __restrict__ pJext,
               const float* __restrict__ pI0,
               const float* __restrict__ pNa,
               const float* __restrict__ pThr,
               float* __restrict__ out)
{
    const int gid = blockIdx.x * blockDim.x + threadIdx.x; // 0..65535

    const double Jext = (double)pJext[0];
    const double I0   = (double)pI0[0];
    const double na   = (double)pNa[0];
    const double ZC   = -0.154 * 270.0;

    WWConst C;
    const double Jd = (double)Jm[0];   // diagonal
    const double Jo = (double)Jm[1];   // off-diagonal
    C.ZJo     = ZC * Jo;
    C.ZCJdmJo = ZC * (Jd - Jo);
    C.decay   = exp(-5.0);             // exp(-DT/TAU_AMPA)
    C.sigma   = na * sqrt((1.0 - exp(-10.0)) / 2.0);
    C.thr     = (double)pThr[0];

    const double base = I0 + Jext * (double)in_sig[gid];
    C.base2 = base * (1.0 - C.decay);

    double s   = 0.1;
    double t1  = base + (double)eps0[gid] * na;    // base + inoise_0
    double tz  = __builtin_fma(ZC, t1, 0.154 * 108.0);
    int    dec = 0x3FFFFFFF;

    // 10-step double-buffered register prefetch; 500 = 25 blocks * 20 steps.
    const float* pu = eps;
    float eA[10], eB[10];
#pragma unroll
    for (int i = 0; i < 10; ++i) eA[i] = pu[(size_t)i * STRIDE + gid];
    pu += (size_t)10 * STRIDE;

    for (int blk = 0; blk < 25; ++blk) {
        const int t0 = blk * 20;
#pragma unroll
        for (int i = 0; i < 10; ++i)
            eB[i] = pu[(size_t)i * STRIDE + gid];
        pu += (size_t)10 * STRIDE;
#pragma unroll
        for (int i = 0; i < 10; ++i)
            ww_step(s, t1, tz, dec, t0 + i, eA[i], C);
        if (blk < 24) {
#pragma unroll
            for (int i = 0; i < 10; ++i)
                eA[i] = pu[(size_t)i * STRIDE + gid];
            pu += (size_t)10 * STRIDE;
        }
#pragma unroll
        for (int i = 0; i < 10; ++i)
            ww_step(s, t1, tz, dec, t0 + 10 + i, eB[i], C);
    }

    const int d = min(dec, T_STEPS - 1);   // never-crossed -> T-1
    out[gid] = ((float)d * 10.0f) / 1000.0f;
}

extern "C" void kernel_launch(void* const* d_in, const int* in_sizes, int n_in,
                              void* d_out, int out_size, void* d_ws, size_t ws_size,
                              hipStream_t stream) {
    const float* in_sig = (const float*)d_in[0];
    const float* eps0   = (const float*)d_in[1];
    const float* eps    = (const float*)d_in[2];
    const float* Jm     = (const float*)d_in[3];
    const float* pJext  = (const float*)d_in[4];
    const float* pI0    = (const float*)d_in[5];
    const float* pNa    = (const float*)d_in[6];
    const float* pThr   = (const float*)d_in[7];
    float* out = (float*)d_out;

    ww_kernel<<<(BATCH * 4) / 256, 256, 0, stream>>>(
        in_sig, eps0, eps, Jm, pJext, pI0, pNa, pThr, out);
}

// Round 12
// 54.727 us; speedup vs baseline: 1.0815x; 1.0416x over previous
//
#include <hip/hip_runtime.h>
#include <math.h>

// Wong-Wang multi-class decision, forward only — FLOAT64 dynamics (r4-r6,r8-r11 passed).
// r12: issue trims + scheduler freedom (balanced issue/latency regime):
//  * t1 state ELIMINATED — spine only consumes tz = ZC*t1 + ZK, and the recursion
//    closes in tz-space: tz = fma(tz, decay, fma(ZCsig, e, K2)),
//    ZCsig = ZC*sigma, K2 = ZC*base2 + ZK*(1-decay).  (-1 f64 fma/step)
//  * sc exponent via fused shift-add: hi = (lo32(tmag) << 20) + 0x3FF00000
//    == (1023+n)<<20 exactly for n in [-36,42].  (-1 int op/step)
//  * paired decision update: (t,t+1) -> 5 ops per 2 steps instead of 6; exact.
//  * __launch_bounds__(256,1): grid pins occupancy at 1 wave/SIMD anyway, so
//    VGPRs are free — unlock the register budget for deeper cross-step scheduling.
// All numeric rewrites are <=1-ulp-class (validated bit-stable band r5->r11).

#define T_STEPS 500
#define BATCH   16384
#define STRIDE  (BATCH * 4)

template <int CTRL>
__device__ __forceinline__ double qperm_d(double v) {
    long long l = __double_as_longlong(v);
    int lo = (int)(l & 0xFFFFFFFFLL);
    int hi = (int)(l >> 32);
    lo = __builtin_amdgcn_mov_dpp(lo, CTRL, 0xF, 0xF, true);
    hi = __builtin_amdgcn_mov_dpp(hi, CTRL, 0xF, 0xF, true);
    return __longlong_as_double(((long long)hi << 32) | (unsigned int)lo);
}

struct WWConst {
    double ZJo, ZCJdmJo;     // ZC*Jo, ZC*(Jd-Jo)
    double ZCsig, K2;        // ZC*sigma, ZC*base2 + ZK*(1-decay)
    double decay, thr;
};

// one dynamics step; returns nothing, updates s and tz (dec handled by caller)
__device__ __forceinline__ void ww_step(
    double& s, double& tz, float e, const WWConst& C)
{
    const double MAGIC = 6755399441055744.0;               // 1.5 * 2^52
    const double L2E   = 1.4426950408889634074;
    const double LN2   = 6.93147180559945286227e-01;
    const double DEN1  = 1.0 + 1e-6;
    const double G     = -(0.00641 / 0.154);               // up2 = G*(1-s)

    // butterfly quad sum (includes own s): sum4 = s0+s1+s2+s3
    double v1   = s + qperm_d<0xB1>(s);
    double sum4 = v1 + qperm_d<0x4E>(v1);
    double w2   = __builtin_fma(C.ZCJdmJo, s, tz);   // ZC*(Jd-Jo)*s + tz
    double up2  = __builtin_fma(-G, s, G);           // G*(1-s), early
    double s9   = 0.9 * s;                           // early
    // z = -0.154*(270x - 108),  x = Jo*sum4 + (Jd-Jo)*s + t1
    double z = __builtin_fma(C.ZJo, sum4, w2);

    double tmag = __builtin_fma(L2E, z, MAGIC);
    double m    = up2 * z;                           // parallel with exp chain
    double nd   = tmag - MAGIC;
    double r    = __builtin_fma(-nd, LN2, z);        // single-constant reduction

    // deg-10 Estrin Taylor for exp(r)
    double r2 = r * r;
    double P0 = 1.0 + r;
    double P1 = __builtin_fma(r, 1.0 / 6.0,      0.5);
    double P2 = __builtin_fma(r, 1.0 / 120.0,    1.0 / 24.0);
    double P3 = __builtin_fma(r, 1.0 / 5040.0,   1.0 / 720.0);
    double P4 = __builtin_fma(r, 1.0 / 362880.0, 1.0 / 40320.0);
    double r4 = r2 * r2;
    double Q0 = __builtin_fma(r2, P1, P0);
    double Q1 = __builtin_fma(r2, P3, P2);
    double Q2 = __builtin_fma(r2, 1.0 / 3628800.0, P4);
    double r8 = r4 * r4;
    double p  = __builtin_fma(r8, Q2, __builtin_fma(r4, Q1, Q0));

    // sc = 2^n: hi word = (lo32(tmag)<<20) + 0x3FF00000  (one v_lshl_add_u32)
    int   nlo = __double2loint(tmag);
    double sc = __hiloint2double((nlo << 20) + 0x3FF00000, 0);

    // den = 1.000001 - p*2^n
    double den = __builtin_fma(-p, sc, DEN1);

    // y ~ 1/den via rcp + folded Newton; cand = m*y0*(2-den*y0) + s9
    double y0   = __builtin_amdgcn_rcp(den);
    double corr = __builtin_fma(-den, y0, 2.0);
    double my0  = m * y0;
    double cand = __builtin_fma(my0, corr, s9);
    s = fmax(cand, s9);                              // relu folded into max

    // noise chain, tz-space only (t1 eliminated):
    tz = __builtin_fma(tz, C.decay,
                       __builtin_fma(C.ZCsig, (double)e, C.K2));
}

__global__ __launch_bounds__(256, 1)
void ww_kernel(const float* __restrict__ in_sig,
               const float* __restrict__ eps0,
               const float* __restrict__ eps,
               const float* __restrict__ Jm,
               const float* __restrict__ pJext,
               const float* __restrict__ pI0,
               const float* __restrict__ pNa,
               const float* __restrict__ pThr,
               float* __restrict__ out)
{
    const int gid = blockIdx.x * blockDim.x + threadIdx.x; // 0..65535

    const double Jext = (double)pJext[0];
    const double I0   = (double)pI0[0];
    const double na   = (double)pNa[0];
    const double ZC   = -0.154 * 270.0;
    const double ZK   =  0.154 * 108.0;

    WWConst C;
    const double Jd = (double)Jm[0];   // diagonal
    const double Jo = (double)Jm[1];   // off-diagonal
    C.ZJo     = ZC * Jo;
    C.ZCJdmJo = ZC * (Jd - Jo);
    C.decay   = exp(-5.0);             // exp(-DT/TAU_AMPA)
    const double sigma = na * sqrt((1.0 - exp(-10.0)) / 2.0);
    C.ZCsig   = ZC * sigma;
    C.thr     = (double)pThr[0];

    const double base  = I0 + Jext * (double)in_sig[gid];
    const double base2 = base * (1.0 - C.decay);
    C.K2 = __builtin_fma(ZC, base2, ZK * (1.0 - C.decay));

    double s   = 0.1;
    double t10 = base + (double)eps0[gid] * na;    // base + inoise_0
    double tz  = __builtin_fma(ZC, t10, ZK);
    int    dec = 0x3FFFFFFF;

    // 10-step double-buffered register prefetch; 500 = 25 blocks * 20 steps.
    const float* pu = eps;
    float eA[10], eB[10];
#pragma unroll
    for (int i = 0; i < 10; ++i) eA[i] = pu[(size_t)i * STRIDE + gid];
    pu += (size_t)10 * STRIDE;

    const double thr = C.thr;
    for (int blk = 0; blk < 25; ++blk) {
        const int t0 = blk * 20;
#pragma unroll
        for (int i = 0; i < 10; ++i)
            eB[i] = pu[(size_t)i * STRIDE + gid];
        pu += (size_t)10 * STRIDE;
#pragma unroll
        for (int i = 0; i < 10; i += 2) {
            ww_step(s, tz, eA[i], C);
            const bool c0 = (s > thr);
            ww_step(s, tz, eA[i + 1], C);
            const bool c1 = (s > thr);
            const int ci = c0 ? (t0 + i) : (c1 ? (t0 + i + 1) : 0x3FFFFFFF);
            dec = min(dec, ci);
        }
        if (blk < 24) {
#pragma unroll
            for (int i = 0; i < 10; ++i)
                eA[i] = pu[(size_t)i * STRIDE + gid];
            pu += (size_t)10 * STRIDE;
        }
#pragma unroll
        for (int i = 0; i < 10; i += 2) {
            ww_step(s, tz, eB[i], C);
            const bool c0 = (s > thr);
            ww_step(s, tz, eB[i + 1], C);
            const bool c1 = (s > thr);
            const int ci = c0 ? (t0 + 10 + i) : (c1 ? (t0 + 11 + i) : 0x3FFFFFFF);
            dec = min(dec, ci);
        }
    }

    const int d = min(dec, T_STEPS - 1);   // never-crossed -> T-1
    out[gid] = ((float)d * 10.0f) / 1000.0f;
}

extern "C" void kernel_launch(void* const* d_in, const int* in_sizes, int n_in,
                              void* d_out, int out_size, void* d_ws, size_t ws_size,
                              hipStream_t stream) {
    const float* in_sig = (const float*)d_in[0];
    const float* eps0   = (const float*)d_in[1];
    const float* eps    = (const float*)d_in[2];
    const float* Jm     = (const float*)d_in[3];
    const float* pJext  = (const float*)d_in[4];
    const float* pI0    = (const float*)d_in[5];
    const float* pNa    = (const float*)d_in[6];
    const float* pThr   = (const float*)d_in[7];
    float* out = (float*)d_out;

    ww_kernel<<<(BATCH * 4) / 256, 256, 0, stream>>>(
        in_sig, eps0, eps, Jm, pJext, pI0, pNa, pThr, out);
}